// Round 14
// baseline (594.855 us; speedup 1.0000x reference)
//
#include <hip/hip_runtime.h>

#define SLEN 4096
#define DIM  200
#define DP   224   // K-dim padded to 7*32
#define DPL  232   // LDS row stride for K-dim tiles
#define VD   208   // d padded to 13*16
#define VTL  72    // Vt / P LDS row stride
#define HKV  2048  // KV half length (2 halves per sequence)

typedef __bf16 bf16t;
typedef bf16t bf16x8 __attribute__((ext_vector_type(8)));
typedef float f32x4 __attribute__((ext_vector_type(4)));

static __device__ __forceinline__ f32x4 mfma16(bf16x8 a, bf16x8 b, f32x4 c) {
    return __builtin_amdgcn_mfma_f32_16x16x32_bf16(a, b, c, 0, 0, 0);
}

// native RNE cast (compiler fuses pairs into v_cvt_pk_bf16_f32 — m240)
static __device__ __forceinline__ unsigned short f2bf(float f) {
    return __builtin_bit_cast(unsigned short, (__bf16)f);
}

static __device__ __forceinline__ float bf2f(unsigned short s) {
    return __uint_as_float((unsigned)s << 16);
}

static __device__ __forceinline__ uint2 pack4(float a, float b, float c, float d) {
    uint2 r;
    r.x = (unsigned)f2bf(a) | ((unsigned)f2bf(b) << 16);
    r.y = (unsigned)f2bf(c) | ((unsigned)f2bf(d) << 16);
    return r;
}

// ---------------------------------------------------------------------------
// Kernel 1: fused QKV projection, W-tile reg-prefetch (T14).
// grid 512: [mod(2) x 256 row-blocks of 64].
// ---------------------------------------------------------------------------
__global__ __launch_bounds__(256, 2)
void proj_kernel(const float* __restrict__ x1, const float* __restrict__ x2,
                 const float* __restrict__ Wq, const float* __restrict__ bq,
                 const float* __restrict__ Wk, const float* __restrict__ bk,
                 const float* __restrict__ Wv, const float* __restrict__ bv,
                 unsigned short* __restrict__ Qg, unsigned short* __restrict__ Kg,
                 unsigned short* __restrict__ Vtg)
{
    __shared__ unsigned short x_lds[64 * DPL];
    __shared__ unsigned short w_lds[64 * DPL];
    __shared__ unsigned short vt_lds[64 * 66];

    const int tid = threadIdx.x;
    const int mod = blockIdx.x >> 8;
    const int rb  = blockIdx.x & 255;
    const int r0  = rb * 64;
    const int bidx = r0 >> 12;
    const int s0  = r0 & 4095;
    const int unit = mod * 4 + bidx;
    const float* __restrict__ x = mod ? x2 : x1;

    const float* const Ws[3] = {Wq, Wk, Wv};
    const float* const bs[3] = {bq, bk, bv};

    // prologue: stage x tile AND W pass-0 tile, zero pads, one barrier
    for (int i = tid; i < 3200; i += 256) {
        int r = i / 50, c = i % 50;
        const float4 v = *(const float4*)(x + (size_t)(r0 + r) * DIM + c * 4);
        *(uint2*)(x_lds + r * DPL + c * 4) = pack4(v.x, v.y, v.z, v.w);
        const float4 w = *(const float4*)(Wq + (size_t)r * DIM + c * 4);  // pass0: t=0, og=r<200
        *(uint2*)(w_lds + r * DPL + c * 4) = pack4(w.x, w.y, w.z, w.w);
    }
    {
        int r = tid >> 2, c4 = tid & 3;
        uint2 z = make_uint2(0u, 0u);
        *(uint2*)(x_lds + r * DPL + 200 + c4 * 4) = z;
        *(uint2*)(x_lds + r * DPL + 216 + c4 * 4) = z;
        *(uint2*)(w_lds + r * DPL + 200 + c4 * 4) = z;
        *(uint2*)(w_lds + r * DPL + 216 + c4 * 4) = z;
    }
    __syncthreads();

    const int wv = tid >> 6, lane = tid & 63, ln = lane & 15, h = lane >> 4;

    bf16x8 afrag[7];
    #pragma unroll
    for (int kk = 0; kk < 7; ++kk)
        afrag[kk] = *(const bf16x8*)(x_lds + (wv * 16 + ln) * DPL + kk * 32 + 8 * h);

    for (int p = 0; p < 12; ++p) {
        const int mmat = p >> 2, t = p & 3;
        const float* bi = bs[mmat];
        const bool has_next = (p + 1) < 12;

        // issue W-prefetch for pass p+1 (13 float4 slots per thread)
        float4 wf[13];
        if (has_next) {
            const int mm1 = (p + 1) >> 2, t1 = (p + 1) & 3;
            const float* W1 = Ws[mm1];
            #pragma unroll
            for (int it = 0; it < 13; ++it) {
                int i = it * 256 + tid;
                wf[it] = make_float4(0.f, 0.f, 0.f, 0.f);
                if (i < 3200) {
                    int r = i / 50, c = i % 50;
                    int og = t1 * 64 + r;
                    if (og < DIM)
                        wf[it] = *(const float4*)(W1 + (size_t)og * DIM + c * 4);
                }
            }
        }

        f32x4 acc[4];
        #pragma unroll
        for (int sub = 0; sub < 4; ++sub) acc[sub] = (f32x4){0.f, 0.f, 0.f, 0.f};
        #pragma unroll
        for (int kk = 0; kk < 7; ++kk) {
            #pragma unroll
            for (int sub = 0; sub < 4; ++sub) {
                bf16x8 bfrag = *(const bf16x8*)(w_lds + (sub * 16 + ln) * DPL + kk * 32 + 8 * h);
                acc[sub] = mfma16(afrag[kk], bfrag, acc[sub]);
            }
        }

        if (mmat < 2) {
            unsigned short* dst = (mmat == 0) ? Qg : Kg;
            #pragma unroll
            for (int sub = 0; sub < 4; ++sub) {
                int og = t * 64 + sub * 16 + ln;
                if (og < DIM) {
                    float bias = bi[og];
                    #pragma unroll
                    for (int r = 0; r < 4; ++r) {
                        int srow = s0 + wv * 16 + 4 * h + r;
                        dst[((size_t)unit * SLEN + srow) * DP + og] = f2bf(acc[sub][r] + bias);
                    }
                }
            }
            __syncthreads();   // all w_lds reads done
        } else {
            // v: stage to LDS then transposed store
            #pragma unroll
            for (int sub = 0; sub < 4; ++sub) {
                int og = t * 64 + sub * 16 + ln;
                float bias = (og < DIM) ? bi[og] : 0.f;
                #pragma unroll
                for (int r = 0; r < 4; ++r) {
                    float val = (og < DIM) ? (acc[sub][r] + bias) : 0.f;
                    vt_lds[(wv * 16 + 4 * h + r) * 66 + sub * 16 + ln] = f2bf(val);
                }
            }
            __syncthreads();
            for (int pp = 0; pp < 2; ++pp) {
                int idx = pp * 256 + tid;
                int dl = idx >> 3, cc = idx & 7;
                int og = t * 64 + dl;
                if (og < VD) {
                    unsigned short tmp[8];
                    #pragma unroll
                    for (int j = 0; j < 8; ++j)
                        tmp[j] = vt_lds[(cc * 8 + j) * 66 + dl];
                    *(uint4*)(Vtg + ((size_t)unit * VD + og) * SLEN + s0 + cc * 8) = *(uint4*)tmp;
                }
            }
            __syncthreads();
        }

        // write prefetched W into w_lds, then make visible
        if (has_next) {
            #pragma unroll
            for (int it = 0; it < 13; ++it) {
                int i = it * 256 + tid;
                if (i < 3200) {
                    int r = i / 50, c = i % 50;
                    *(uint2*)(w_lds + r * DPL + c * 4) =
                        pack4(wf[it].x, wf[it].y, wf[it].z, wf[it].w);
                }
            }
            __syncthreads();
        }
    }
}

// ---------------------------------------------------------------------------
// Kernel 2: flash attention, KV-split by 2.  R7 shape (512 thr, 8 waves,
// 16 q-rows/wave) + T14 reg-prefetch staging + T5 setprio + native casts.
// grid 512 = hf(2) x 32 Q-tiles(128) x 8 units; u = bx&7 XCD/L2 pinning.
// ---------------------------------------------------------------------------
__global__ __launch_bounds__(512, 4)
void attn_kernel(const unsigned short* __restrict__ Qg,
                 const unsigned short* __restrict__ Kg,
                 const unsigned short* __restrict__ Vtg,
                 unsigned short* __restrict__ Ap,
                 float2* __restrict__ Mlg)
{
    __shared__ unsigned short k_lds[64 * DPL];       // 29.0 KB
    __shared__ unsigned short vt_lds[VD * VTL];      // 29.3 KB
    __shared__ unsigned short p_lds[8 * 16 * VTL];   // 18.4 KB

    const int tid = threadIdx.x;
    const int u   = blockIdx.x & 7;
    const int qt  = (blockIdx.x >> 3) & 31;
    const int hf  = blockIdx.x >> 8;
    const int wv = tid >> 6, lane = tid & 63, ln = lane & 15, h = lane >> 4;
    const size_t ubase = (size_t)u * SLEN;

    bf16x8 qfrag[7];
    {
        const size_t qoff = (ubase + qt * 128 + wv * 16 + ln) * DP;
        #pragma unroll
        for (int kk = 0; kk < 7; ++kk)
            qfrag[kk] = *(const bf16x8*)(Qg + qoff + kk * 32 + 8 * h);
    }

    float mrun[4], lrun[4];
    #pragma unroll
    for (int r = 0; r < 4; ++r) { mrun[r] = -1e30f; lrun[r] = 0.f; }
    f32x4 acc[13];
    #pragma unroll
    for (int d = 0; d < 13; ++d) acc[d] = (f32x4){0.f, 0.f, 0.f, 0.f};

    const float scale = 0.07071067811865475f;  // 1/sqrt(200)
    const int t_beg = hf * HKV;
    const int t_end = t_beg + HKV;

    // prologue: stage tile 0 directly
    #pragma unroll
    for (int it = 0; it < 4; ++it) {
        int i = it * 512 + tid;
        if (i < 1792) {
            int r = i / 28, c = i % 28;
            *(uint4*)(k_lds + r * DPL + c * 8) =
                *(const uint4*)(Kg + (ubase + t_beg + r) * DP + c * 8);
        }
        if (i < 1664) {
            int r = i >> 3, c = i & 7;
            *(uint4*)(vt_lds + r * VTL + c * 8) =
                *(const uint4*)(Vtg + ((size_t)u * VD + r) * SLEN + t_beg + c * 8);
        }
    }
    __syncthreads();

    for (int t0 = t_beg; t0 < t_end; t0 += 64) {
        const bool has_next = (t0 + 64) < t_end;

        // T14: issue next tile's global loads NOW; latency hides under compute
        uint4 pk[4], pv[4];
        if (has_next) {
            const int t1 = t0 + 64;
            #pragma unroll
            for (int it = 0; it < 4; ++it) {
                int i = it * 512 + tid;
                if (i < 1792) {
                    int r = i / 28, c = i % 28;
                    pk[it] = *(const uint4*)(Kg + (ubase + t1 + r) * DP + c * 8);
                }
                if (i < 1664) {
                    int r = i >> 3, c = i & 7;
                    pv[it] = *(const uint4*)(Vtg + ((size_t)u * VD + r) * SLEN + t1 + c * 8);
                }
            }
        }

        // scores: S[s, t] = sum_k q[s,k] K[t,k]
        f32x4 sc[4];
        #pragma unroll
        for (int sub = 0; sub < 4; ++sub) sc[sub] = (f32x4){0.f, 0.f, 0.f, 0.f};
        __builtin_amdgcn_s_setprio(1);
        #pragma unroll
        for (int kk = 0; kk < 7; ++kk) {
            #pragma unroll
            for (int sub = 0; sub < 4; ++sub) {
                bf16x8 bfrag = *(const bf16x8*)(k_lds + (sub * 16 + ln) * DPL + kk * 32 + 8 * h);
                sc[sub] = mfma16(qfrag[kk], bfrag, sc[sub]);
            }
        }
        __builtin_amdgcn_s_setprio(0);

        // online softmax (row = 4h+r across 16-lane group)
        float mxs[4];
        #pragma unroll
        for (int r = 0; r < 4; ++r) {
            float mx = fmaxf(fmaxf(sc[0][r], sc[1][r]), fmaxf(sc[2][r], sc[3][r]));
            mx = fmaxf(mx, __shfl_xor(mx, 1));
            mx = fmaxf(mx, __shfl_xor(mx, 2));
            mx = fmaxf(mx, __shfl_xor(mx, 4));
            mx = fmaxf(mx, __shfl_xor(mx, 8));
            mxs[r] = mx * scale;
        }

        // T13 defer-max: only rescale when some row's max grew by > 8
        int need = (mxs[0] > mrun[0] + 8.f) | (mxs[1] > mrun[1] + 8.f) |
                   (mxs[2] > mrun[2] + 8.f) | (mxs[3] > mrun[3] + 8.f);
        if (__any(need)) {
            #pragma unroll
            for (int r = 0; r < 4; ++r) {
                float mnew = fmaxf(mrun[r], mxs[r]);
                float alpha = __expf(mrun[r] - mnew);
                lrun[r] *= alpha;
                #pragma unroll
                for (int d = 0; d < 13; ++d) acc[d][r] *= alpha;
                mrun[r] = mnew;
            }
        }

        #pragma unroll
        for (int r = 0; r < 4; ++r) {
            float rsum = 0.f;
            #pragma unroll
            for (int sub = 0; sub < 4; ++sub) {
                float p = __expf(sc[sub][r] * scale - mrun[r]);
                rsum += p;
                p_lds[wv * (16 * VTL) + (4 * h + r) * VTL + sub * 16 + ln] = f2bf(p);
            }
            rsum += __shfl_xor(rsum, 1);
            rsum += __shfl_xor(rsum, 2);
            rsum += __shfl_xor(rsum, 4);
            rsum += __shfl_xor(rsum, 8);
            lrun[r] += rsum;
        }

        // PV: A[s, d] += sum_t P[s,t] Vt[d,t]
        __builtin_amdgcn_s_setprio(1);
        #pragma unroll
        for (int ks = 0; ks < 2; ++ks) {
            bf16x8 pfrag = *(const bf16x8*)(p_lds + wv * (16 * VTL) + ln * VTL + ks * 32 + 8 * h);
            #pragma unroll
            for (int d = 0; d < 13; ++d) {
                bf16x8 bfrag = *(const bf16x8*)(vt_lds + (d * 16 + ln) * VTL + ks * 32 + 8 * h);
                acc[d] = mfma16(pfrag, bfrag, acc[d]);
            }
        }
        __builtin_amdgcn_s_setprio(0);

        __syncthreads();   // all LDS reads of tile t0 complete

        // write prefetched tile t0+64 (vmcnt wait auto-inserted), make visible
        if (has_next) {
            #pragma unroll
            for (int it = 0; it < 4; ++it) {
                int i = it * 512 + tid;
                if (i < 1792) {
                    int r = i / 28, c = i % 28;
                    *(uint4*)(k_lds + r * DPL + c * 8) = pk[it];
                }
                if (i < 1664) {
                    int r = i >> 3, c = i & 7;
                    *(uint4*)(vt_lds + r * VTL + c * 8) = pv[it];
                }
            }
        }
        __syncthreads();
    }

    // store unnormalized A (bf16) + (m, l) per row
    const int slab = hf * 8 + u;
    unsigned short* Adst = Ap + (size_t)slab * SLEN * VD;
    #pragma unroll
    for (int r = 0; r < 4; ++r) {
        int srow = qt * 128 + wv * 16 + 4 * h + r;
        #pragma unroll
        for (int d = 0; d < 13; ++d)
            Adst[(size_t)srow * VD + d * 16 + ln] = f2bf(acc[d][r]);
        if (ln == 0)
            Mlg[(size_t)slab * SLEN + srow] = make_float2(mrun[r], lrun[r]);
    }
}

// ---------------------------------------------------------------------------
// Kernel 3: combine KV-halves + fused = a1 + a2, then @ Wo^T + bo.
// grid 256 row-blocks of 64.  Hoisted combine weights + Wo reg-prefetch.
// ---------------------------------------------------------------------------
__global__ __launch_bounds__(256, 2)
void out_kernel(const unsigned short* __restrict__ Ap,
                const float2* __restrict__ Mlg,
                const float* __restrict__ Wo,
                const float* __restrict__ bo, float* __restrict__ out)
{
    __shared__ unsigned short a_lds[64 * DPL];
    __shared__ unsigned short w_lds[64 * DPL];
    __shared__ float4 ml_s[64];

    const int tid = threadIdx.x;
    const int r0 = blockIdx.x * 64;
    const int bidx = r0 >> 12;
    const int s0 = r0 & 4095;

    const unsigned short* A1a = Ap + (size_t)(bidx)      * SLEN * VD;
    const unsigned short* A1b = Ap + (size_t)(8 + bidx)  * SLEN * VD;
    const unsigned short* A2a = Ap + (size_t)(4 + bidx)  * SLEN * VD;
    const unsigned short* A2b = Ap + (size_t)(12 + bidx) * SLEN * VD;

    if (tid < 64) {
        int srow = s0 + tid;
        float2 ml1a = Mlg[(size_t)(bidx)      * SLEN + srow];
        float2 ml1b = Mlg[(size_t)(8 + bidx)  * SLEN + srow];
        float2 ml2a = Mlg[(size_t)(4 + bidx)  * SLEN + srow];
        float2 ml2b = Mlg[(size_t)(12 + bidx) * SLEN + srow];
        float M1 = fmaxf(ml1a.x, ml1b.x);
        float w1a = __expf(ml1a.x - M1), w1b = __expf(ml1b.x - M1);
        float inv1 = 1.f / (ml1a.y * w1a + ml1b.y * w1b);
        float M2 = fmaxf(ml2a.x, ml2b.x);
        float w2a = __expf(ml2a.x - M2), w2b = __expf(ml2b.x - M2);
        float inv2 = 1.f / (ml2a.y * w2a + ml2b.y * w2b);
        ml_s[tid] = make_float4(w1a * inv1, w1b * inv1, w2a * inv2, w2b * inv2);
    }
    __syncthreads();

    // combine: 64 rows x 25 col-chunks of 8
    for (int i = tid; i < 1600; i += 256) {
        int r = i / 25, c = i % 25;
        int srow = s0 + r;
        size_t off = (size_t)srow * VD + c * 8;
        float4 s = ml_s[r];

        uint4 pa = *(const uint4*)(A1a + off);
        uint4 pb = *(const uint4*)(A1b + off);
        uint4 qa = *(const uint4*)(A2a + off);
        uint4 qb = *(const uint4*)(A2b + off);

        const unsigned* pau = &pa.x; const unsigned* pbu = &pb.x;
        const unsigned* qau = &qa.x; const unsigned* qbu = &qb.x;
        float f[8];
        #pragma unroll
        for (int j = 0; j < 4; ++j) {
            f[2*j]   = (bf2f((unsigned short)(pau[j] & 0xffff)) * s.x + bf2f((unsigned short)(pbu[j] & 0xffff)) * s.y)
                     + (bf2f((unsigned short)(qau[j] & 0xffff)) * s.z + bf2f((unsigned short)(qbu[j] & 0xffff)) * s.w);
            f[2*j+1] = (bf2f((unsigned short)(pau[j] >> 16))    * s.x + bf2f((unsigned short)(pbu[j] >> 16))    * s.y)
                     + (bf2f((unsigned short)(qau[j] >> 16))    * s.z + bf2f((unsigned short)(qbu[j] >> 16))    * s.w);
        }
        *(uint2*)(a_lds + r * DPL + c * 8)     = pack4(f[0], f[1], f[2], f[3]);
        *(uint2*)(a_lds + r * DPL + c * 8 + 4) = pack4(f[4], f[5], f[6], f[7]);
    }
    // stage Wo pass 0 (rows 0..63, all < DIM)
    for (int i = tid; i < 3200; i += 256) {
        int r = i / 50, c = i % 50;
        const float4 v = *(const float4*)(Wo + (size_t)r * DIM + c * 4);
        *(uint2*)(w_lds + r * DPL + c * 4) = pack4(v.x, v.y, v.z, v.w);
    }
    {
        int r = tid >> 2, c4 = tid & 3;
        uint2 z = make_uint2(0u, 0u);
        *(uint2*)(a_lds + r * DPL + 200 + c4 * 4) = z;
        *(uint2*)(a_lds + r * DPL + 216 + c4 * 4) = z;
        *(uint2*)(w_lds + r * DPL + 200 + c4 * 4) = z;
        *(uint2*)(w_lds + r * DPL + 216 + c4 * 4) = z;
    }
    __syncthreads();

    const int wv = tid >> 6, lane = tid & 63, ln = lane & 15, h = lane >> 4;
    bf16x8 afrag[7];
    #pragma unroll
    for (int kk = 0; kk < 7; ++kk)
        afrag[kk] = *(const bf16x8*)(a_lds + (wv * 16 + ln) * DPL + kk * 32 + 8 * h);

    for (int t = 0; t < 4; ++t) {
        const bool has_next = (t + 1) < 4;
        float4 wf[13];
        if (has_next) {
            #pragma unroll
            for (int it = 0; it < 13; ++it) {
                int i = it * 256 + tid;
                wf[it] = make_float4(0.f, 0.f, 0.f, 0.f);
                if (i < 3200) {
                    int r = i / 50, c = i % 50;
                    int og = (t + 1) * 64 + r;
                    if (og < DIM)
                        wf[it] = *(const float4*)(Wo + (size_t)og * DIM + c * 4);
                }
            }
        }

        f32x4 acc[4];
        #pragma unroll
        for (int sub = 0; sub < 4; ++sub) acc[sub] = (f32x4){0.f, 0.f, 0.f, 0.f};
        #pragma unroll
        for (int kk = 0; kk < 7; ++kk) {
            #pragma unroll
            for (int sub = 0; sub < 4; ++sub) {
                bf16x8 bfrag = *(const bf16x8*)(w_lds + (sub * 16 + ln) * DPL + kk * 32 + 8 * h);
                acc[sub] = mfma16(afrag[kk], bfrag, acc[sub]);
            }
        }

        #pragma unroll
        for (int sub = 0; sub < 4; ++sub) {
            int og = t * 64 + sub * 16 + ln;
            if (og < DIM) {
                float bias = bo[og];
                #pragma unroll
                for (int r = 0; r < 4; ++r) {
                    int row = r0 + wv * 16 + 4 * h + r;
                    out[(size_t)row * DIM + og] = acc[sub][r] + bias;
                }
            }
        }
        __syncthreads();

        if (has_next) {
            #pragma unroll
            for (int it = 0; it < 13; ++it) {
                int i = it * 256 + tid;
                if (i < 3200) {
                    int r = i / 50, c = i % 50;
                    *(uint2*)(w_lds + r * DPL + c * 4) =
                        pack4(wf[it].x, wf[it].y, wf[it].z, wf[it].w);
                }
            }
            __syncthreads();
        }
    }
}

// ---------------------------------------------------------------------------
extern "C" void kernel_launch(void* const* d_in, const int* in_sizes, int n_in,
                              void* d_out, int out_size, void* d_ws, size_t ws_size,
                              hipStream_t stream)
{
    const float* x1 = (const float*)d_in[0];
    const float* x2 = (const float*)d_in[1];
    const float* Wq = (const float*)d_in[2];
    const float* bq = (const float*)d_in[3];
    const float* Wk = (const float*)d_in[4];
    const float* bk = (const float*)d_in[5];
    const float* Wv = (const float*)d_in[6];
    const float* bv = (const float*)d_in[7];
    const float* Wo = (const float*)d_in[8];
    const float* bo = (const float*)d_in[9];

    unsigned short* Qg  = (unsigned short*)d_ws;
    unsigned short* Kg  = Qg + (size_t)8 * SLEN * DP;
    unsigned short* Vtg = Kg + (size_t)8 * SLEN * DP;
    unsigned short* Apg = Vtg + (size_t)8 * VD * SLEN;             // 16 slabs bf16
    float2*         Mlg = (float2*)(Apg + (size_t)16 * SLEN * VD); // 16 x S x (m,l)

    proj_kernel<<<dim3(512), dim3(256), 0, stream>>>(x1, x2, Wq, bq, Wk, bk, Wv, bv,
                                                     Qg, Kg, Vtg);
    attn_kernel<<<dim3(512), dim3(512), 0, stream>>>(Qg, Kg, Vtg, Apg, Mlg);
    out_kernel<<<dim3(256), dim3(256), 0, stream>>>(Apg, Mlg, Wo, bo, (float*)d_out);
}